// Round 12
// baseline (248.247 us; speedup 1.0000x reference)
//
#include <hip/hip_runtime.h>
#include <cmath>

#define NN    512
#define SEQL  64
#define DIN   128
#define NH    4
#define NE    4096
#define DOUTN 128
#define LOG2E 1.44269504088896340736f

typedef __attribute__((ext_vector_type(4))) float f32x4;
typedef __attribute__((ext_vector_type(8))) short bf16x8;

#define GLOAD_LDS16(g, l) __builtin_amdgcn_global_load_lds( \
    (const __attribute__((address_space(1))) unsigned int*)(g), \
    (__attribute__((address_space(3))) unsigned int*)(l), 16, 0, 0)

__device__ __forceinline__ float lrelu(float v) { return v >= 0.f ? v : 0.2f * v; }

__device__ __forceinline__ unsigned short f2bf(float f) {
    union { float f; unsigned u; } x; x.f = f;
    unsigned r = (x.u + 0x7FFFu + ((x.u >> 16) & 1u)) >> 16;
    return (unsigned short)r;
}
__device__ __forceinline__ float bf2f(unsigned short h) {
    union { unsigned u; float f; } x; x.u = ((unsigned)h) << 16;
    return x.f;
}

// ---------------- preprocess: x[N][S][D] -> H f32 [S][N][D] + Hbf bf16 [S][N][D]
__global__ __launch_bounds__(256) void preprocess_k(const float* __restrict__ x,
                                                    float* __restrict__ H,
                                                    unsigned short* __restrict__ Hbf) {
    int tid = blockIdx.x * 256 + threadIdx.x;
    int base = tid * 4;
    int d0 = base & 127;
    int s  = (base >> 7) & 63;
    int n  = base >> 13;
    float4 v = *(const float4*)(x + base);
    if (d0 == 0) {
        v.y = log10f(v.y + 1.f); v.z = log10f(v.z + 1.f); v.w = log10f(v.w + 1.f);
    } else {
        v.x = log10f(v.x + 1.f); v.y = log10f(v.y + 1.f);
        v.z = log10f(v.z + 1.f); v.w = log10f(v.w + 1.f);
    }
    if (v.x != v.x) v.x = 0.f;
    if (v.y != v.y) v.y = 0.f;
    if (v.z != v.z) v.z = 0.f;
    if (v.w != v.w) v.w = 0.f;
    size_t off = ((size_t)s * NN + n) * DIN + d0;
    *(float4*)(H + off) = v;
    ushort4 b; b.x = f2bf(v.x); b.y = f2bf(v.y); b.z = f2bf(v.z); b.w = f2bf(v.w);
    *(ushort4*)(Hbf + off) = b;
}

// ---------------- weight cast + transpose + concat
__global__ __launch_bounds__(256) void castw_k(const float* __restrict__ W1s, const float* __restrict__ W1d,
                                               const float* __restrict__ W2s, const float* __restrict__ W2d,
                                               const float* __restrict__ Wfc,
                                               const float* __restrict__ b1s, const float* __restrict__ b1d,
                                               const float* __restrict__ b2s, const float* __restrict__ b2d,
                                               unsigned short* __restrict__ T1sd, unsigned short* __restrict__ T2sd,
                                               unsigned short* __restrict__ Tfc,
                                               float* __restrict__ bc1, float* __restrict__ bc2) {
    int i = blockIdx.x * 256 + threadIdx.x;
    if (i < 131072) {
        int n = i >> 7, k = i & 127;
        T1sd[i] = f2bf(n < 512 ? W1s[k * 512 + n] : W1d[k * 512 + (n - 512)]);
    } else if (i < 262144) {
        int j = i - 131072; int n = j >> 9, k = j & 511;
        T2sd[j] = f2bf(n < 128 ? W2s[k * 128 + n] : W2d[k * 128 + (n - 128)]);
    } else if (i < 278528) {
        int j = i - 262144; int n = j >> 7, k = j & 127;
        Tfc[j] = f2bf(Wfc[k * 128 + n]);
    } else if (i < 279552) {
        int j = i - 278528;
        bc1[j] = j < 512 ? b1s[j] : b1d[j - 512];
    } else if (i < 279808) {
        int j = i - 279552;
        bc2[j] = j < 128 ? b2s[j] : b2d[j - 128];
    }
}

// ---------------- CSR build (src-id CSR)
__global__ void csr_init_k(int* counts, int* fill) {
    int t = threadIdx.x;
    counts[t] = 0; fill[t] = 0;
}
__global__ void csr_hist_k(const int* __restrict__ dst, int* counts) {
    int e = blockIdx.x * 256 + threadIdx.x;
    if (e < NE) atomicAdd(&counts[dst[e]], 1);
}
__global__ void csr_scan_k(const int* __restrict__ counts, int* __restrict__ row_ptr) {
    int l = threadIdx.x;                              // 64 lanes
    int c[8]; int lsum = 0;
#pragma unroll
    for (int j = 0; j < 8; ++j) { c[j] = counts[l * 8 + j]; lsum += c[j]; }
    int pre = lsum;
    for (int o = 1; o < 64; o <<= 1) {
        int v = __shfl_up(pre, o);
        if (l >= o) pre += v;
    }
    int acc = pre - lsum;
#pragma unroll
    for (int j = 0; j < 8; ++j) { row_ptr[l * 8 + j] = acc; acc += c[j]; }
    if (l == 63) row_ptr[512] = acc;
}
__global__ void csr_scatter_k(const int* __restrict__ src, const int* __restrict__ dst,
                              const int* __restrict__ row_ptr, int* fill, int* esrc) {
    int e = blockIdx.x * 256 + threadIdx.x;
    if (e < NE) {
        int dn = dst[e];
        int pos = atomicAdd(&fill[dn], 1);
        esrc[row_ptr[dn] + pos] = src[e];
    }
}
// ---------------- degree counting-sort: order[] = nodes sorted by degree (load balance)
__global__ void node_sort_k(const int* __restrict__ row_ptr, int* __restrict__ order) {
    __shared__ int bins[64];
    __shared__ int starts[64];
    int t = threadIdx.x;                  // 512
    if (t < 64) bins[t] = 0;
    __syncthreads();
    int deg = row_ptr[t + 1] - row_ptr[t];
    int b = deg < 63 ? deg : 63;
    atomicAdd(&bins[b], 1);
    __syncthreads();
    if (t < 64) {                         // wave 0: exclusive scan over 64 bins
        int v = bins[t];
        int pre = v;
        for (int o = 1; o < 64; o <<= 1) {
            int u = __shfl_up(pre, o);
            if (t >= o) pre += u;
        }
        starts[t] = pre - v;
        bins[t] = 0;                      // reuse as fill counters
    }
    __syncthreads();
    int pos = atomicAdd(&bins[b], 1);
    order[starts[b] + pos] = t;
}

// ---------------- bf16 MFMA GEMM: C = A[M,K] @ BT[N,K]^T + bias
// global_load_lds staging: swizzle applied to GLOBAL source chunk, LDS linear per-wave (m97/m173).
// MODE 0: single bf16 out. MODE 1: f32 remap out (final FC). MODE 2: split bf16 (C1|C2 at half).
template<int MODE>
__global__ __launch_bounds__(256) void gemm_k(const unsigned short* __restrict__ A,
                                              const unsigned short* __restrict__ BT,
                                              const float* __restrict__ bias,
                                              void* __restrict__ C1v, void* __restrict__ C2v,
                                              int M, int N, int K, int s0, int half) {
    __shared__ unsigned short As[8192];   // 128 rows x 64 cols bf16 (phys-swizzled), 16 KB
    __shared__ unsigned short Bs[8192];
    int t = threadIdx.x;
    int w = t >> 6, l = t & 63;
    int wr = w >> 1, wc = w & 1;
    int m0 = blockIdx.y * 128, n0 = blockIdx.x * 128;

    f32x4 acc[4][4];
#pragma unroll
    for (int i = 0; i < 4; ++i)
#pragma unroll
        for (int j = 0; j < 4; ++j) acc[i][j] = (f32x4){0.f, 0.f, 0.f, 0.f};

    for (int k0 = 0; k0 < K; k0 += 64) {
        __syncthreads();                   // previous iteration's ds_reads complete
#pragma unroll
        for (int c = 0; c < 4; ++c) {
            int rows_base = w * 32 + c * 8;
            int row = rows_base + (l >> 3);
            int chunk = (l & 7) ^ (row & 7);          // pre-swizzled source chunk
            const unsigned short* ga = A  + (size_t)(m0 + row) * K + k0 + chunk * 8;
            const unsigned short* gb = BT + (size_t)(n0 + row) * K + k0 + chunk * 8;
            GLOAD_LDS16(ga, As + rows_base * 64);     // lane lands at base + l*16B (linear)
            GLOAD_LDS16(gb, Bs + rows_base * 64);
        }
        __syncthreads();                   // vmcnt drained -> tiles ready
#pragma unroll
        for (int ks = 0; ks < 2; ++ks) {
            bf16x8 af[4], bfr[4];
#pragma unroll
            for (int i = 0; i < 4; ++i) {
                int row = wr * 64 + i * 16 + (l & 15);
                int colb = (ks * 64 + ((l >> 4) * 16)) ^ ((row & 7) << 4);
                af[i] = *(const bf16x8*)((const char*)As + (row << 7) + colb);
            }
#pragma unroll
            for (int j = 0; j < 4; ++j) {
                int row = wc * 64 + j * 16 + (l & 15);
                int colb = (ks * 64 + ((l >> 4) * 16)) ^ ((row & 7) << 4);
                bfr[j] = *(const bf16x8*)((const char*)Bs + (row << 7) + colb);
            }
#pragma unroll
            for (int i = 0; i < 4; ++i)
#pragma unroll
                for (int j = 0; j < 4; ++j)
                    acc[i][j] = __builtin_amdgcn_mfma_f32_16x16x32_bf16(af[i], bfr[j], acc[i][j], 0, 0, 0);
        }
    }

    float bl[4];
#pragma unroll
    for (int j = 0; j < 4; ++j) bl[j] = bias[n0 + wc * 64 + j * 16 + (l & 15)];
#pragma unroll
    for (int i = 0; i < 4; ++i) {
#pragma unroll
        for (int j = 0; j < 4; ++j) {
            int n = n0 + wc * 64 + j * 16 + (l & 15);
#pragma unroll
            for (int jj = 0; jj < 4; ++jj) {
                int m = m0 + wr * 64 + i * 16 + (l >> 4) * 4 + jj;
                float v = acc[i][j][jj] + bl[j];
                if (MODE == 1) {
                    int sl = m >> 9, node = m & 511;
                    ((float*)C1v)[((size_t)node * SEQL + (s0 + sl)) * DOUTN + n] = v;
                } else if (MODE == 2) {
                    unsigned short* dp = (unsigned short*)(n < half ? C1v : C2v);
                    int nn = n < half ? n : n - half;
                    dp[(size_t)m * half + nn] = f2bf(v);
                } else {
                    ((unsigned short*)C1v)[(size_t)m * N + n] = f2bf(v);
                }
            }
        }
    }
}

// ---------------- XCD-affine (s, idx) decode
__device__ __forceinline__ void s_swizzle(int bid, int sc, int B, int logB, int& s, int& idx) {
    if ((sc & 7) == 0) {
        int xcd = bid & 7;
        int j = bid >> 3;
        int grp = j >> logB;
        idx = j & (B - 1);
        s = grp * 8 + xcd;
    } else {
        s = bid >> logB;
        idx = bid & (B - 1);
    }
}

// ---------------- FUSED layer-1: logits + branchless online softmax + agg.
// One wave per (s, order[node]); batch-4 gathers; exp2 softmax.
__global__ __launch_bounds__(256) void fused_l1_k(const unsigned short* __restrict__ FS,
                                                  const unsigned short* __restrict__ FD,
                                                  const int* __restrict__ row_ptr,
                                                  const int* __restrict__ esrc,
                                                  const int* __restrict__ order,
                                                  const float* __restrict__ attn,
                                                  unsigned short* __restrict__ G1,
                                                  int sc) {
    int wv = threadIdx.x >> 6, l = threadIdx.x & 63;
    int s, nb;
    s_swizzle(blockIdx.x, sc, 128, 7, s, nb);
    int n = order[nb * 4 + wv];            // degree-sorted assignment
    int e0 = row_ptr[n], e1 = row_ptr[n + 1];
    float at[8], fdv[8];
    bf16x8 fdr = *(const bf16x8*)(FD + ((size_t)s * NN + n) * 512 + l * 8);
#pragma unroll
    for (int k = 0; k < 8; ++k) {
        at[k] = attn[l * 8 + k] * LOG2E;
        fdv[k] = bf2f((unsigned short)fdr[k]);
    }
    const unsigned short* fsbase = FS + (size_t)s * NN * 512 + l * 8;
    float m_run = -INFINITY, den = 0.f;
    float acc[8] = {};

    auto process = [&](bf16x8 raw) {
        float fv[8], part = 0.f;
#pragma unroll
        for (int k = 0; k < 8; ++k) {
            fv[k] = bf2f((unsigned short)raw[k]);
            part += at[k] * lrelu(fv[k] + fdv[k]);
        }
        part += __shfl_xor(part, 1);
        part += __shfl_xor(part, 2);
        part += __shfl_xor(part, 4);
        part += __shfl_xor(part, 8);       // scaled logit, uniform per 16-lane head group
        float m_new = fmaxf(m_run, part);  // branchless update (no exec-mask split)
        float sc_ = exp2f(m_run - m_new);  // first edge: exp2(-inf)=0
        float wgt = exp2f(part - m_new);
        den = den * sc_ + wgt;
#pragma unroll
        for (int k = 0; k < 8; ++k) acc[k] = acc[k] * sc_ + wgt * fv[k];
        m_run = m_new;
    };

    for (int j = e0; j < e1; j += 4) {     // wave-uniform bounds
        int rem = e1 - j;
        bf16x8 r0, r1, r2, r3;
        r0 = *(const bf16x8*)(fsbase + (size_t)esrc[j] * 512);
        if (rem > 1) r1 = *(const bf16x8*)(fsbase + (size_t)esrc[j + 1] * 512);
        if (rem > 2) r2 = *(const bf16x8*)(fsbase + (size_t)esrc[j + 2] * 512);
        if (rem > 3) r3 = *(const bf16x8*)(fsbase + (size_t)esrc[j + 3] * 512);
        process(r0);
        if (rem > 1) process(r1);
        if (rem > 2) process(r2);
        if (rem > 3) process(r3);
    }
    float inv = 1.f / den;
    bf16x8 o8;
#pragma unroll
    for (int k = 0; k < 8; ++k) o8[k] = (short)f2bf(acc[k] * inv);
    *(bf16x8*)(G1 + ((size_t)s * NN + n) * 512 + l * 8) = o8;
}

// ---------------- FUSED layer-2: logits + branchless softmax + agg + residual + LN.
__global__ __launch_bounds__(256) void fused_l2_k(const unsigned short* __restrict__ FS,
                                                  const unsigned short* __restrict__ FD,
                                                  const int* __restrict__ row_ptr,
                                                  const int* __restrict__ esrc,
                                                  const int* __restrict__ order,
                                                  const float* __restrict__ attn,
                                                  const float* __restrict__ H,
                                                  const float* __restrict__ gamma,
                                                  const float* __restrict__ beta,
                                                  unsigned short* __restrict__ Y,
                                                  int s0, int sc) {
    int wv = threadIdx.x >> 6, l = threadIdx.x & 63;
    int s, nb;
    s_swizzle(blockIdx.x, sc, 128, 7, s, nb);
    int n = order[nb * 4 + wv];
    int e0 = row_ptr[n], e1 = row_ptr[n + 1];
    float a0 = attn[l * 2] * LOG2E, a1 = attn[l * 2 + 1] * LOG2E;
    ushort2 fdr = *(const ushort2*)(FD + ((size_t)s * NN + n) * 128 + l * 2);
    float fd0 = bf2f(fdr.x), fd1 = bf2f(fdr.y);
    const unsigned short* fb = FS + (size_t)s * NN * 128 + l * 2;
    float m_run = -INFINITY, den = 0.f, c0 = 0.f, c1 = 0.f;

    auto process = [&](ushort2 uv) {
        float f0 = bf2f(uv.x), f1 = bf2f(uv.y);
        float part = a0 * lrelu(f0 + fd0) + a1 * lrelu(f1 + fd1);
#pragma unroll
        for (int o = 1; o < 64; o <<= 1) part += __shfl_xor(part, o);
        float m_new = fmaxf(m_run, part);
        float sc_ = exp2f(m_run - m_new);
        float wgt = exp2f(part - m_new);
        den = den * sc_ + wgt;
        c0 = c0 * sc_ + wgt * f0;
        c1 = c1 * sc_ + wgt * f1;
        m_run = m_new;
    };

    for (int j = e0; j < e1; j += 4) {
        int rem = e1 - j;
        ushort2 u0, u1, u2, u3;
        u0 = *(const ushort2*)(fb + (size_t)esrc[j] * 128);
        if (rem > 1) u1 = *(const ushort2*)(fb + (size_t)esrc[j + 1] * 128);
        if (rem > 2) u2 = *(const ushort2*)(fb + (size_t)esrc[j + 2] * 128);
        if (rem > 3) u3 = *(const ushort2*)(fb + (size_t)esrc[j + 3] * 128);
        process(u0);
        if (rem > 1) process(u1);
        if (rem > 2) process(u2);
        if (rem > 3) process(u3);
    }
    float inv = 1.f / den;
    float g0 = c0 * inv, g1 = c1 * inv;
    float2 xp = *(const float2*)(H + ((size_t)(s0 + s) * NN + n) * DIN + l * 2);
    if (g0 != g0) g0 = xp.x;
    if (g1 != g1) g1 = xp.y;
    float o0 = xp.x + g0, o1 = xp.y + g1;
    float ssum = o0 + o1, ssq = o0 * o0 + o1 * o1;
#pragma unroll
    for (int o = 32; o > 0; o >>= 1) { ssum += __shfl_xor(ssum, o); ssq += __shfl_xor(ssq, o); }
    float mu  = ssum * (1.f / 128.f);
    float var = ssq * (1.f / 128.f) - mu * mu;
    float rstd = rsqrtf(var + 1e-5f);
    float y0 = (o0 - mu) * rstd * gamma[l * 2]     + beta[l * 2];
    float y1 = (o1 - mu) * rstd * gamma[l * 2 + 1] + beta[l * 2 + 1];
    ushort2 yo; yo.x = f2bf(y0); yo.y = f2bf(y1);
    *(ushort2*)(Y + ((size_t)s * NN + n) * 128 + l * 2) = yo;
}

extern "C" void kernel_launch(void* const* d_in, const int* in_sizes, int n_in,
                              void* d_out, int out_size, void* d_ws, size_t ws_size,
                              hipStream_t stream) {
    const float* x     = (const float*)d_in[0];
    const int*   src   = (const int*)d_in[1];
    const int*   dst   = (const int*)d_in[2];
    const float* W1s   = (const float*)d_in[3];
    const float* b1s   = (const float*)d_in[4];
    const float* W1d   = (const float*)d_in[5];
    const float* b1d   = (const float*)d_in[6];
    const float* attn1 = (const float*)d_in[7];
    const float* W2s   = (const float*)d_in[8];
    const float* b2s   = (const float*)d_in[9];
    const float* W2d   = (const float*)d_in[10];
    const float* b2d   = (const float*)d_in[11];
    const float* attn2 = (const float*)d_in[12];
    const float* gamma = (const float*)d_in[13];
    const float* beta  = (const float*)d_in[14];
    const float* Wfc   = (const float*)d_in[15];
    const float* bfc   = (const float*)d_in[16];
    float* out = (float*)d_out;

    char* p = (char*)d_ws;
    float*          H    = (float*)p;                          // 16,777,216 B
    unsigned short* Hbf  = (unsigned short*)(p + 16777216);    //  8,388,608 B
    unsigned short* T1sd = (unsigned short*)(p + 25165824);    //    262,144 B
    unsigned short* T2sd = (unsigned short*)(p + 25427968);    //    262,144 B
    unsigned short* Tfc  = (unsigned short*)(p + 25690112);    //     32,768 B
    float*          bc1  = (float*)(p + 25722880);             //      4,096 B
    float*          bc2  = (float*)(p + 25726976);             //      1,024 B
    int* counts  = (int*)(p + 25728000);                       // 512
    int* row_ptr = counts + 512;                               // 513
    int* fill    = row_ptr + 513;                              // 512
    int* esrc    = fill + 512;                                 // 4096
    int* order   = esrc + 4096;                                // 512 (ends < base)
    const size_t base = 25755648;

    // per-seq-chunk bytes: 3*524288 + 3*131072 = 1,966,080
    int SC = 1;
    const int cand[7] = {64, 32, 16, 8, 4, 2, 1};
    for (int i = 0; i < 7; ++i)
        if (base + (size_t)cand[i] * 1966080ull <= ws_size) { SC = cand[i]; break; }

    unsigned short* FSb  = (unsigned short*)(p + base);
    unsigned short* FDb  = FSb  + (size_t)SC * 262144;
    unsigned short* G1b  = FDb  + (size_t)SC * 262144;
    unsigned short* FS2b = G1b  + (size_t)SC * 262144;
    unsigned short* FD2b = FS2b + (size_t)SC * 65536;
    unsigned short* Ybf  = FD2b + (size_t)SC * 65536;

    preprocess_k<<<4096, 256, 0, stream>>>(x, H, Hbf);
    castw_k<<<1094, 256, 0, stream>>>(W1s, W1d, W2s, W2d, Wfc, b1s, b1d, b2s, b2d,
                                      T1sd, T2sd, Tfc, bc1, bc2);
    csr_init_k<<<1, 512, 0, stream>>>(counts, fill);
    csr_hist_k<<<NE / 256, 256, 0, stream>>>(dst, counts);
    csr_scan_k<<<1, 64, 0, stream>>>(counts, row_ptr);
    node_sort_k<<<1, 512, 0, stream>>>(row_ptr, order);
    csr_scatter_k<<<NE / 256, 256, 0, stream>>>(src, dst, row_ptr, fill, esrc);

    for (int s0 = 0; s0 < SEQL; s0 += SC) {
        const unsigned short* Hc = Hbf + (size_t)s0 * NN * DIN;
        int M = SC * NN;
        gemm_k<2><<<dim3(8, SC * 4), 256, 0, stream>>>(Hc, T1sd, bc1, FSb, FDb, M, 1024, 128, 0, 512);
        fused_l1_k<<<SC * 128, 256, 0, stream>>>(FSb, FDb, row_ptr, esrc, order, attn1, G1b, SC);
        gemm_k<2><<<dim3(2, SC * 4), 256, 0, stream>>>(G1b, T2sd, bc2, FS2b, FD2b, M, 256, 512, 0, 128);
        fused_l2_k<<<SC * 128, 256, 0, stream>>>(FS2b, FD2b, row_ptr, esrc, order, attn2,
                                                 H, gamma, beta, Ybf, s0, SC);
        gemm_k<1><<<dim3(1, SC * 4), 256, 0, stream>>>(Ybf, Tfc, bfc, out, nullptr, M, 128, 128, s0, 0);
    }
}